// Round 11
// baseline (404.313 us; speedup 1.0000x reference)
//
#include <hip/hip_runtime.h>
#include <hip/hip_bf16.h>
#include <math.h>

typedef __bf16 bf16x8 __attribute__((ext_vector_type(8)));
typedef __bf16 bf16x4 __attribute__((ext_vector_type(4)));
typedef float  f32x4  __attribute__((ext_vector_type(4)));

#define T_SEQ 2048
#define NH    16
#define HD    64
#define DM    1024
// softmax logits pre-scaled by 1/sqrt(64) * log2(e) so we can use exp2
#define QSCALE 0.18033688011112043f

__device__ __forceinline__ f32x4 mfma16(bf16x8 a, bf16x8 b, f32x4 c) {
    return __builtin_amdgcn_mfma_f32_16x16x32_bf16(a, b, c, 0, 0, 0);
}

// async global->LDS, 16B per lane. LDS dest is wave-uniform base + lane*16
// (our staging layout is exactly that). __syncthreads() drains vmcnt.
__device__ __forceinline__ void gl2lds(const void* g, void* l) {
    __builtin_amdgcn_global_load_lds(
        (const __attribute__((address_space(1))) void*)g,
        (__attribute__((address_space(3))) void*)l, 16, 0, 0);
}

// ================= prep (one dispatch) =================
__device__ __forceinline__ void tsplit_body(const float* __restrict__ in,
                                            __bf16* __restrict__ oh, __bf16* __restrict__ ol,
                                            int K, int N, int n0, int k0, int SPLIT,
                                            float* tile /* [64][65] LDS */)
{
    const int tid = threadIdx.x;
#pragma unroll
    for (int it = 0; it < 2; ++it) {
        int r = it * 32 + (tid >> 3), c8 = (tid & 7) * 8;
        f32x4 a0 = *(const f32x4*)&in[(size_t)(k0 + r) * N + n0 + c8];
        f32x4 a1 = *(const f32x4*)&in[(size_t)(k0 + r) * N + n0 + c8 + 4];
#pragma unroll
        for (int j = 0; j < 4; ++j) { tile[r * 65 + c8 + j] = a0[j]; tile[r * 65 + c8 + 4 + j] = a1[j]; }
    }
    __syncthreads();
    const int n = tid >> 2, kb = (tid & 3) * 16;
    bf16x8 h0, h1, l0, l1;
#pragma unroll
    for (int j = 0; j < 8; ++j) {
        float v0 = tile[(kb + j) * 65 + n], v1 = tile[(kb + 8 + j) * 65 + n];
        __bf16 hb0 = (__bf16)v0, hb1 = (__bf16)v1;
        h0[j] = hb0; h1[j] = hb1;
        if (SPLIT) { l0[j] = (__bf16)(v0 - (float)hb0); l1[j] = (__bf16)(v1 - (float)hb1); }
    }
    size_t o = (size_t)(n0 + n) * K + k0 + kb;
    *(bf16x8*)&oh[o] = h0; *(bf16x8*)&oh[o + 8] = h1;
    if (SPLIT) { *(bf16x8*)&ol[o] = l0; *(bf16x8*)&ol[o + 8] = l1; }
}

__global__ __launch_bounds__(256)
void prep(const float* __restrict__ x, const float* __restrict__ Wq,
          const float* __restrict__ Wkv, const float* __restrict__ Wv,
          const float* __restrict__ Wo, const float* __restrict__ Wk,
          const float* __restrict__ Wkr, const float* __restrict__ bk,
          __bf16* xh, __bf16* xl, __bf16* Wqt_h, __bf16* Wqt_l,
          __bf16* Wkvt_h, __bf16* Wkvt_l, __bf16* Wvt, __bf16* Wot,
          __bf16* W2th, __bf16* W2tl, float* b2)
{
    __shared__ float tile[64 * 65];
    const int g = blockIdx.x, tid = threadIdx.x;
    if (g < 2048) {                       // split x -> xh/xl
        size_t idx = ((size_t)g * 256 + tid) * 8;
        f32x4 a0 = *(const f32x4*)&x[idx];
        f32x4 a1 = *(const f32x4*)&x[idx + 4];
        bf16x8 h, l;
#pragma unroll
        for (int j = 0; j < 4; ++j) {
            __bf16 h0 = (__bf16)a0[j];
            h[j]     = h0; l[j]     = (__bf16)(a0[j] - (float)h0);
            __bf16 h1 = (__bf16)a1[j];
            h[4 + j] = h1; l[4 + j] = (__bf16)(a1[j] - (float)h1);
        }
        *(bf16x8*)&xh[idx] = h;
        *(bf16x8*)&xl[idx] = l;
    } else if (g < 2304) {                // Wq -> [N,K] split
        int i = g - 2048;
        tsplit_body(Wq, Wqt_h, Wqt_l, 1024, 1024, (i & 15) * 64, (i >> 4) * 64, 1, tile);
    } else if (g < 2368) {                // Wkv -> split
        int i = g - 2304;
        tsplit_body(Wkv, Wkvt_h, Wkvt_l, 1024, 256, (i & 3) * 64, (i >> 2) * 64, 1, tile);
    } else if (g < 2432) {                // Wv -> trunc
        int i = g - 2368;
        tsplit_body(Wv, Wvt, nullptr, 256, 1024, (i & 15) * 64, (i >> 4) * 64, 0, tile);
    } else if (g < 2688) {                // Wo -> trunc
        int i = g - 2432;
        tsplit_body(Wo, Wot, nullptr, 1024, 1024, (i & 15) * 64, (i >> 4) * 64, 0, tile);
    } else {                              // W2 = Wk_h @ Wkr (transposed split) + b2
        int o    = (g - 2688) * 256 + tid;
        int rowk = o >> 10, col = o & 1023;
        int h = col >> 6, d = col & 63;
        float acc = 0.0f;
        if (rowk < 256) {
#pragma unroll 8
            for (int j = 0; j < 64; ++j)
                acc += Wk[(size_t)rowk * DM + h * HD + j] * Wkr[j * HD + d];
            __bf16 hb = (__bf16)acc;
            W2th[(size_t)col * 256 + rowk] = hb;
            W2tl[(size_t)col * 256 + rowk] = (__bf16)(acc - (float)hb);
        } else {
#pragma unroll 8
            for (int j = 0; j < 64; ++j)
                acc += bk[h * HD + j] * Wkr[j * HD + d];
            b2[col] = acc;
        }
    }
}

// ================= 128x128 GEMM body =================
// A bf16 [M,K] (hi + optional lo), B bf16 [N,K] (hi + optional lo)
// OUTM: 0 bf16 | 1 fp32 | 2 dual split bf16
// EPI:  0 bias | 1 RoPE*QSCALE split-out | 2 bias then *t | 3 v->vtg transpose
// Staging: async global_load_lds width=16 (layout is wave-base + lane*16).
// NOTE: never pass nullptr for a lo pointer with DUAL*=1 (r5-r7 bug).
// NOTE: branches of ONE dispatch must never write memory another branch reads
// (r9 bug: v wrote vtg overlaying xlo read by q). q+kv / k+v merges are safe.
template <int DUALA, int DUALB, int OUTM, int EPI>
__device__ __forceinline__
void gemm_body(char* smem,
               const __bf16* __restrict__ Ahi, const __bf16* __restrict__ Alo,
               const __bf16* __restrict__ Bhi, const __bf16* __restrict__ Blo,
               const float* __restrict__ bias, void* __restrict__ Cp,
               void* __restrict__ Cp2, int m0, int n0, int N, int K)
{
    __bf16* Ah = (__bf16*)smem;               // [128][32]
    __bf16* Al = (__bf16*)(smem + 8192);
    __bf16* Bh = (__bf16*)(smem + 16384);     // [128][32] = [n][k]
    __bf16* Bl = (__bf16*)(smem + 24576);

    const int tid  = threadIdx.x;
    const int w    = tid >> 6;
    const int lane = tid & 63;
    const int l16  = lane & 15;
    const int quad = lane >> 4;
    const int wy   = w >> 1, wx = w & 1;

    f32x4 acc[4][4];
#pragma unroll
    for (int i = 0; i < 4; ++i)
#pragma unroll
        for (int j = 0; j < 4; ++j) acc[i][j] = (f32x4)0.0f;

    for (int k0 = 0; k0 < K; k0 += 32) {
        __syncthreads();
#pragma unroll
        for (int i = 0; i < 2; ++i) {
            int s = i * 256 + tid, row = s >> 2, c8 = (s & 3) * 8;
            gl2lds(&Ahi[(size_t)(m0 + row) * K + k0 + c8], &Ah[row * 32 + c8]);
            if (DUALA) gl2lds(&Alo[(size_t)(m0 + row) * K + k0 + c8], &Al[row * 32 + c8]);
            gl2lds(&Bhi[(size_t)(n0 + row) * K + k0 + c8], &Bh[row * 32 + c8]);
            if (DUALB) gl2lds(&Blo[(size_t)(n0 + row) * K + k0 + c8], &Bl[row * 32 + c8]);
        }
        __syncthreads();

        bf16x8 bfh[4], bfl[4];
#pragma unroll
        for (int ct = 0; ct < 4; ++ct) {
            bfh[ct] = *(const bf16x8*)&Bh[(wx * 64 + ct * 16 + l16) * 32 + quad * 8];
            if (DUALB) bfl[ct] = *(const bf16x8*)&Bl[(wx * 64 + ct * 16 + l16) * 32 + quad * 8];
        }
#pragma unroll
        for (int mf = 0; mf < 4; ++mf) {
            bf16x8 ah = *(const bf16x8*)&Ah[(wy * 64 + mf * 16 + l16) * 32 + quad * 8];
            bf16x8 al;
            if (DUALA) al = *(const bf16x8*)&Al[(wy * 64 + mf * 16 + l16) * 32 + quad * 8];
#pragma unroll
            for (int ct = 0; ct < 4; ++ct) {
                acc[mf][ct] = mfma16(ah, bfh[ct], acc[mf][ct]);
                if (DUALA) acc[mf][ct] = mfma16(al, bfh[ct], acc[mf][ct]);
                if (DUALB) acc[mf][ct] = mfma16(ah, bfl[ct], acc[mf][ct]);
            }
        }
    }

    float bias_v[4];
#pragma unroll
    for (int ct = 0; ct < 4; ++ct)
        bias_v[ct] = bias ? bias[n0 + wx * 64 + ct * 16 + l16] : 0.0f;

    if (EPI == 1) {  // RoPE (q): pair (d, d+32) = (ct, ct+2); *QSCALE; split out
        __bf16* Chi = (__bf16*)Cp;
        __bf16* Clo = (__bf16*)Cp2;
#pragma unroll
        for (int mf = 0; mf < 4; ++mf) {
#pragma unroll
            for (int r = 0; r < 4; ++r) {
                int   m = m0 + wy * 64 + mf * 16 + quad * 4 + r;
                float t = (float)(m & (T_SEQ - 1));
#pragma unroll
                for (int ct = 0; ct < 2; ++ct) {
                    int   d   = ct * 16 + l16;
                    float inv = powf(10000.0f, -(float)d * (1.0f / 32.0f));
                    float sv, cv;
                    sincosf(t * inv, &sv, &cv);
                    float lo = acc[mf][ct][r]     + bias_v[ct];
                    float hi = acc[mf][ct + 2][r] + bias_v[ct + 2];
                    float v0 = (lo * cv - hi * sv) * QSCALE;
                    float v1 = (hi * cv + lo * sv) * QSCALE;
                    size_t i0 = (size_t)m * N + n0 + wx * 64 + d;
                    size_t i1 = i0 + 32;
                    __bf16 h0 = (__bf16)v0, h1 = (__bf16)v1;
                    Chi[i0] = h0; Clo[i0] = (__bf16)(v0 - (float)h0);
                    Chi[i1] = h1; Clo[i1] = (__bf16)(v1 - (float)h1);
                }
            }
        }
    } else if (EPI == 3) {  // v: write vtg[bh][d][t] via per-wave LDS transpose
        __syncthreads();
        __bf16* vt = (__bf16*)(smem + w * 9216);   // [64][72]
#pragma unroll
        for (int mf = 0; mf < 4; ++mf)
#pragma unroll
            for (int ct = 0; ct < 4; ++ct)
#pragma unroll
                for (int r = 0; r < 4; ++r)
                    vt[(ct * 16 + l16) * 72 + mf * 16 + quad * 4 + r] =
                        (__bf16)(acc[mf][ct][r] + bias_v[ct]);
        const int bb   = m0 >> 11;
        const int head = (n0 + wx * 64) >> 6;
        const int bh   = bb * 16 + head;
        __bf16* out    = (__bf16*)Cp;
        size_t  gbase  = ((size_t)(bh * 64 + lane)) * T_SEQ + (m0 & (T_SEQ - 1)) + wy * 64;
#pragma unroll
        for (int j8 = 0; j8 < 8; ++j8)
            *(bf16x8*)&out[gbase + j8 * 8] = *(const bf16x8*)&vt[lane * 72 + j8 * 8];
    } else {
#pragma unroll
        for (int mf = 0; mf < 4; ++mf) {
#pragma unroll
            for (int r = 0; r < 4; ++r) {
                int   m     = m0 + wy * 64 + mf * 16 + quad * 4 + r;
                float scale = (EPI == 2) ? (float)(m & (T_SEQ - 1)) : 1.0f;
#pragma unroll
                for (int ct = 0; ct < 4; ++ct) {
                    float  v   = (acc[mf][ct][r] + bias_v[ct]) * scale;
                    size_t idx = (size_t)m * N + n0 + wx * 64 + ct * 16 + l16;
                    if (OUTM == 1)      ((float*)Cp)[idx]  = v;
                    else if (OUTM == 0) ((__bf16*)Cp)[idx] = (__bf16)v;
                    else {
                        __bf16 hb = (__bf16)v;
                        ((__bf16*)Cp)[idx]  = hb;
                        ((__bf16*)Cp2)[idx] = (__bf16)(v - (float)hb);
                    }
                }
            }
        }
    }
}

// merged kv + q gemm: grid (10, 32) = 320 blocks (kv first so it fills early)
__global__ __launch_bounds__(256)
void gemm_qkv(const __bf16* xh, const __bf16* xl,
              const __bf16* Wqt_h, const __bf16* Wqt_l, const float* bq,
              __bf16* qhi, __bf16* qlo,
              const __bf16* Wkvt_h, const __bf16* Wkvt_l, const float* bkv,
              __bf16* kvhi, __bf16* kvlo)
{
    __shared__ __attribute__((aligned(16))) char smem[36864];
    const int m0 = blockIdx.y * 128;
    if (blockIdx.x < 2)
        gemm_body<1, 1, 2, 0>(smem, xh, xl, Wkvt_h, Wkvt_l, bkv, kvhi, kvlo,
                              m0, blockIdx.x * 128, 256, 1024);
    else
        gemm_body<1, 1, 2, 1>(smem, xh, xl, Wqt_h, Wqt_l, bq, qhi, qlo,
                              m0, (blockIdx.x - 2) * 128, 1024, 1024);
}

// merged k + v gemm: grid (16, 32) = 512 blocks. Safe merge: v writes vtg
// (overlays xlo) and no branch here reads xlo (q is in the previous dispatch).
__global__ __launch_bounds__(256)
void gemm_kv2(const __bf16* kvhi, const __bf16* kvlo,
              const __bf16* W2th, const __bf16* W2tl, const float* b2,
              __bf16* khi, __bf16* klo,
              const __bf16* Wvt, const float* bv, __bf16* vtg)
{
    __shared__ __attribute__((aligned(16))) char smem[36864];
    const int m0 = blockIdx.y * 128;
    if (blockIdx.x < 8)
        gemm_body<1, 1, 2, 2>(smem, kvhi, kvlo, W2th, W2tl, b2, khi, klo,
                              m0, blockIdx.x * 128, 1024, 256);
    else
        gemm_body<1, 0, 0, 3>(smem, kvhi, kvlo, Wvt, Wvt, bv, vtg, nullptr,
                              m0, (blockIdx.x - 8) * 128, 1024, 256);
}

// o gemm: grid (8, 32)
__global__ __launch_bounds__(256)
void gemm_o(const __bf16* ybb, const __bf16* Wot, const float* bo, float* out)
{
    __shared__ __attribute__((aligned(16))) char smem[36864];
    gemm_body<0, 0, 1, 0>(smem, ybb, ybb, Wot, Wot, bo, out, nullptr,
                          blockIdx.y * 128, blockIdx.x * 128, 1024, 1024);
}

// ================= flash attention v6 =================
// Transposed dataflow (S^T = K Q^T, O^T = V^T P^T), cross-quad shfl row
// reductions, 16B-aligned P rows. OCCUPANCY REDESIGN vs v5: single-buffered
// K/V + register prefetch + 2 barriers/step + ONE shared per-wave P buffer
// (softmax+PV per-frag sequential) -> LDS 36.9 KB -> 4 blocks/CU (16 waves/CU,
// 2x v5). Loads for step j+1 issue at barrier1, commit after barrier2, so
// global latency overlaps the whole QK+softmax+PV phase (same window as dbuf).
#define KSP 72
#define PSP 72
__global__ __launch_bounds__(256, 4)
void attn_v6(const __bf16* __restrict__ qhi, const __bf16* __restrict__ qlo,
             const __bf16* __restrict__ khi, const __bf16* __restrict__ klo,
             const __bf16* __restrict__ vtg, __bf16* __restrict__ yb)
{
    __shared__ __attribute__((aligned(16))) __bf16 Kh[64 * KSP];
    __shared__ __attribute__((aligned(16))) __bf16 Kl[64 * KSP];
    __shared__ __attribute__((aligned(16))) __bf16 Vt[64 * KSP];   // [d][key]
    __shared__ __attribute__((aligned(16))) __bf16 Pw[4][16 * PSP]; // per-wave [qrow][key]

    const int tid  = threadIdx.x;
    const int w    = tid >> 6;
    const int lane = tid & 63;
    const int l16  = lane & 15;
    const int quad = lane >> 4;

    // bh = g&31 (XCD-stable); tiles paired (15-2a, 2(a-8)) so co-resident pairs sum to 34 steps
    const int g  = blockIdx.x;
    const int bh = g & 31, a = g >> 5;
    const int tile = (a < 8) ? (15 - 2 * a) : (2 * (a - 8));
    const int b = bh >> 4, h = bh & 15;
    const int q0 = tile * 128;

    // Q B-frags (pre-scaled by QSCALE), 2 frags x 2 k-halves
    bf16x8 qh[2][2], ql[2][2];
#pragma unroll
    for (int f = 0; f < 2; ++f) {
        const int    qrow = q0 + 64 * f + 16 * w + l16;
        const size_t qoff = (size_t)(b * T_SEQ + qrow) * DM + h * HD;
#pragma unroll
        for (int s = 0; s < 2; ++s) {
            qh[f][s] = *(const bf16x8*)&qhi[qoff + s * 32 + quad * 8];
            ql[f][s] = *(const bf16x8*)&qlo[qoff + s * 32 + quad * 8];
        }
    }

    f32x4 o[2][4];
#pragma unroll
    for (int f = 0; f < 2; ++f)
#pragma unroll
        for (int i = 0; i < 4; ++i) o[f][i] = (f32x4)0.0f;
    float m_i[2] = {-1e30f, -1e30f}, l_i[2] = {0.f, 0.f};

    const int srow = tid >> 3, sc8 = (tid & 7) * 8;
    bf16x8 kr[2], lr[2], vr[2];
    __bf16* pw = &Pw[w][0];

    // prologue: load step 0 into regs, commit to LDS (barrier1 publishes it)
#pragma unroll
    for (int it = 0; it < 2; ++it) {
        int    r  = it * 32 + srow;
        size_t gk = (size_t)(b * T_SEQ + r) * DM + h * HD + sc8;
        kr[it] = *(const bf16x8*)&khi[gk];
        lr[it] = *(const bf16x8*)&klo[gk];
        vr[it] = *(const bf16x8*)&vtg[(size_t)(bh * HD + r) * T_SEQ + sc8];
    }
#pragma unroll
    for (int it = 0; it < 2; ++it) {
        int r = it * 32 + srow;
        *(bf16x8*)&Kh[r * KSP + sc8] = kr[it];
        *(bf16x8*)&Kl[r * KSP + sc8] = lr[it];
        *(bf16x8*)&Vt[r * KSP + sc8] = vr[it];
    }

    const int jmax = q0 + 64;
    for (int j0 = 0; j0 <= jmax; j0 += 64) {
        const bool act0 = (j0 <= q0);   // frag0 fully masked on final step
        const bool pre  = (j0 + 64 <= jmax);
        __syncthreads();                // barrier1: commits of step j-1 visible

        // issue next step's global loads (latency overlaps all compute below)
        if (pre) {
#pragma unroll
            for (int it = 0; it < 2; ++it) {
                int    r  = it * 32 + srow;
                size_t gk = (size_t)(b * T_SEQ + j0 + 64 + r) * DM + h * HD + sc8;
                kr[it] = *(const bf16x8*)&khi[gk];
                lr[it] = *(const bf16x8*)&klo[gk];
                vr[it] = *(const bf16x8*)&vtg[(size_t)(bh * HD + r) * T_SEQ + j0 + 64 + sc8];
            }
        }

        // S^T = K Q^T: rows=keys (kc,quad,reg), cols=qrows (l16)
        f32x4 sa[2][4];
#pragma unroll
        for (int f = 0; f < 2; ++f)
#pragma unroll
            for (int i = 0; i < 4; ++i) sa[f][i] = (f32x4)0.0f;
#pragma unroll
        for (int s = 0; s < 2; ++s) {
#pragma unroll
            for (int kc = 0; kc < 4; ++kc) {
                bf16x8 kh = *(const bf16x8*)&Kh[(kc * 16 + l16) * KSP + s * 32 + quad * 8];
                bf16x8 kv = *(const bf16x8*)&Kl[(kc * 16 + l16) * KSP + s * 32 + quad * 8];
                sa[1][kc] = mfma16(kh, qh[1][s], sa[1][kc]);
                sa[1][kc] = mfma16(kv, qh[1][s], sa[1][kc]);
                sa[1][kc] = mfma16(kh, ql[1][s], sa[1][kc]);
                if (act0) {
                    sa[0][kc] = mfma16(kh, qh[0][s], sa[0][kc]);
                    sa[0][kc] = mfma16(kv, qh[0][s], sa[0][kc]);
                    sa[0][kc] = mfma16(kh, ql[0][s], sa[0][kc]);
                }
            }
        }

        // per-frag: online softmax (cross-quad shfl_xor(16,32) row reductions,
        // r5 NaN fix) then immediately P->LDS + PV, sharing ONE per-wave pw
#pragma unroll
        for (int f = 0; f < 2; ++f) {
            if (f == 0 && !act0) continue;
            const int  qrow = q0 + 64 * f + 16 * w + l16;
            const bool need = (j0 + 63 > q0 + 64 * f + 16 * w);
            if (need) {
#pragma unroll
                for (int kc = 0; kc < 4; ++kc)
#pragma unroll
                    for (int r = 0; r < 4; ++r)
                        if (j0 + kc * 16 + quad * 4 + r > qrow) sa[f][kc][r] = -1e30f;
            }
            float mx = -1e30f;
#pragma unroll
            for (int kc = 0; kc < 4; ++kc)
#pragma unroll
                for (int r = 0; r < 4; ++r) mx = fmaxf(mx, sa[f][kc][r]);
            mx = fmaxf(mx, __shfl_xor(mx, 16));
            mx = fmaxf(mx, __shfl_xor(mx, 32));
            float mn    = fmaxf(fmaxf(m_i[f], mx), -1e20f);
            float alpha = exp2f(m_i[f] - mn);
            m_i[f] = mn;
            float rs = 0.f;
#pragma unroll
            for (int kc = 0; kc < 4; ++kc) {
                float p0 = exp2f(sa[f][kc][0] - mn);
                float p1 = exp2f(sa[f][kc][1] - mn);
                float p2 = exp2f(sa[f][kc][2] - mn);
                float p3 = exp2f(sa[f][kc][3] - mn);
                rs += (p0 + p1) + (p2 + p3);
                bf16x4 pk = { (__bf16)p0, (__bf16)p1, (__bf16)p2, (__bf16)p3 };
                *(bf16x4*)&pw[l16 * PSP + kc * 16 + quad * 4] = pk;
            }
            rs += __shfl_xor(rs, 16);
            rs += __shfl_xor(rs, 32);
            l_i[f] = l_i[f] * alpha + rs;
#pragma unroll
            for (int dc = 0; dc < 4; ++dc) o[f][dc] *= alpha;

            // O^T += V^T P^T for this frag (pw is per-wave: no block sync)
#pragma unroll
            for (int s = 0; s < 2; ++s) {
                bf16x8 pb = *(const bf16x8*)&pw[l16 * PSP + s * 32 + quad * 8];
#pragma unroll
                for (int dc = 0; dc < 4; ++dc) {
                    bf16x8 va = *(const bf16x8*)&Vt[(dc * 16 + l16) * KSP + s * 32 + quad * 8];
                    o[f][dc] = mfma16(va, pb, o[f][dc]);
                }
            }
        }

        __syncthreads();                // barrier2: all waves done reading K/V
        if (pre) {
#pragma unroll
            for (int it = 0; it < 2; ++it) {
                int r = it * 32 + srow;
                *(bf16x8*)&Kh[r * KSP + sc8] = kr[it];
                *(bf16x8*)&Kl[r * KSP + sc8] = lr[it];
                *(bf16x8*)&Vt[r * KSP + sc8] = vr[it];
            }
        }
    }

    // epilogue: normalize, transpose via per-wave pw, coalesced store
#pragma unroll
    for (int f = 0; f < 2; ++f) {
        float invl = 1.0f / l_i[f];
#pragma unroll
        for (int dc = 0; dc < 4; ++dc) {
            bf16x4 ov = { (__bf16)(o[f][dc][0] * invl), (__bf16)(o[f][dc][1] * invl),
                          (__bf16)(o[f][dc][2] * invl), (__bf16)(o[f][dc][3] * invl) };
            *(bf16x4*)&pw[l16 * PSP + dc * 16 + quad * 4] = ov;
        }
        const int qrl  = lane >> 2;          // 0..15
        const int dch  = (lane & 3) * 16;    // 0,16,32,48
        const int qrow = q0 + 64 * f + 16 * w + qrl;
        const __bf16* src = &pw[qrl * PSP + dch];
        __bf16*       dst = &yb[(size_t)(b * T_SEQ + qrow) * DM + h * HD + dch];
        *(bf16x8*)dst       = *(const bf16x8*)src;
        *(bf16x8*)(dst + 8) = *(const bf16x8*)(src + 8);
    }
}

extern "C" void kernel_launch(void* const* d_in, const int* in_sizes, int n_in,
                              void* d_out, int out_size, void* d_ws, size_t ws_size,
                              hipStream_t stream)
{
    (void)in_sizes; (void)n_in; (void)out_size; (void)ws_size;

    const float* x   = (const float*)d_in[0];
    const float* Wq  = (const float*)d_in[2];
    const float* bq  = (const float*)d_in[3];
    const float* Wkv = (const float*)d_in[4];
    const float* bkv = (const float*)d_in[5];
    const float* Wk  = (const float*)d_in[6];
    const float* bk  = (const float*)d_in[7];
    const float* Wv  = (const float*)d_in[8];
    const float* bv  = (const float*)d_in[9];
    const float* Wo  = (const float*)d_in[10];
    const float* bo  = (const float*)d_in[11];
    const float* Wkr = (const float*)d_in[12];

    const int    BT = 2 * T_SEQ;   // 4096
    const size_t MB = 1024 * 1024;
    char* base = (char*)d_ws;

    __bf16* xhi    = (__bf16*)(base +  0 * MB);
    __bf16* xlo    = (__bf16*)(base +  8 * MB);
    __bf16* qhi    = (__bf16*)(base + 16 * MB);
    __bf16* qlo    = (__bf16*)(base + 24 * MB);
    __bf16* Wqt_h  = (__bf16*)(base + 32 * MB);
    __bf16* Wqt_l  = (__bf16*)(base + 34 * MB);
    __bf16* Wkvt_h = (__bf16*)(base + 36 * MB);
    __bf16* Wkvt_l = (__bf16*)(base + 37 * MB);
    __bf16* kvhi   = (__bf16*)(base + 38 * MB);
    __bf16* kvlo   = (__bf16*)(base + 40 * MB);
    __bf16* W2t_h  = (__bf16*)(base + 42 * MB);
    __bf16* W2t_l  = (__bf16*)(base + 42 * MB + 512 * 1024);
    __bf16* Wvt    = (__bf16*)(base + 43 * MB);
    __bf16* Wot    = (__bf16*)(base + 43 * MB + 512 * 1024);
    float*  b2     = (float*) (base + 45 * MB + 512 * 1024);
    __bf16* vtg    = (__bf16*)(base +  8 * MB);               // overlays xlo (dead after gemm_qkv)
    __bf16* ybb    = (__bf16*)(base +  0 * MB);               // overlays xhi (dead after gemm_qkv)
    __bf16* khi    = (__bf16*)d_out;                          // d_out as scratch
    __bf16* klo    = (__bf16*)d_out + (size_t)BT * DM;        // overwritten by o gemm

    dim3 blk(256);
    prep<<<3716, blk, 0, stream>>>(x, Wq, Wkv, Wv, Wo, Wk, Wkr, bk,
                                   xhi, xlo, Wqt_h, Wqt_l, Wkvt_h, Wkvt_l,
                                   Wvt, Wot, W2t_h, W2t_l, b2);
    gemm_qkv<<<dim3(10, 32), blk, 0, stream>>>(xhi, xlo, Wqt_h, Wqt_l, bq, qhi, qlo,
                                               Wkvt_h, Wkvt_l, bkv, kvhi, kvlo);
    gemm_kv2<<<dim3(16, 32), blk, 0, stream>>>(kvhi, kvlo, W2t_h, W2t_l, b2,
                                               khi, klo, Wvt, bv, vtg);
    attn_v6<<<512, blk, 0, stream>>>(qhi, qlo, khi, klo, vtg, ybb);
    gemm_o<<<dim3(8, 32), blk, 0, stream>>>(ybb, Wot, bo, (float*)d_out);
}

// Round 12
// 300.677 us; speedup vs baseline: 1.3447x; 1.3447x over previous
//
#include <hip/hip_runtime.h>
#include <hip/hip_bf16.h>
#include <math.h>

typedef __bf16 bf16x8 __attribute__((ext_vector_type(8)));
typedef __bf16 bf16x4 __attribute__((ext_vector_type(4)));
typedef float  f32x4  __attribute__((ext_vector_type(4)));

#define T_SEQ 2048
#define NH    16
#define HD    64
#define DM    1024
// softmax logits pre-scaled by 1/sqrt(64) * log2(e) so we can use exp2
#define QSCALE 0.18033688011112043f

__device__ __forceinline__ f32x4 mfma16(bf16x8 a, bf16x8 b, f32x4 c) {
    return __builtin_amdgcn_mfma_f32_16x16x32_bf16(a, b, c, 0, 0, 0);
}

// async global->LDS, 16B per lane. LDS dest is wave-uniform base + lane*16
// (our staging layout is exactly that). __syncthreads() drains vmcnt.
__device__ __forceinline__ void gl2lds(const void* g, void* l) {
    __builtin_amdgcn_global_load_lds(
        (const __attribute__((address_space(1))) void*)g,
        (__attribute__((address_space(3))) void*)l, 16, 0, 0);
}

// ================= prep (one dispatch) =================
__device__ __forceinline__ void tsplit_body(const float* __restrict__ in,
                                            __bf16* __restrict__ oh, __bf16* __restrict__ ol,
                                            int K, int N, int n0, int k0, int SPLIT,
                                            float* tile /* [64][65] LDS */)
{
    const int tid = threadIdx.x;
#pragma unroll
    for (int it = 0; it < 2; ++it) {
        int r = it * 32 + (tid >> 3), c8 = (tid & 7) * 8;
        f32x4 a0 = *(const f32x4*)&in[(size_t)(k0 + r) * N + n0 + c8];
        f32x4 a1 = *(const f32x4*)&in[(size_t)(k0 + r) * N + n0 + c8 + 4];
#pragma unroll
        for (int j = 0; j < 4; ++j) { tile[r * 65 + c8 + j] = a0[j]; tile[r * 65 + c8 + 4 + j] = a1[j]; }
    }
    __syncthreads();
    const int n = tid >> 2, kb = (tid & 3) * 16;
    bf16x8 h0, h1, l0, l1;
#pragma unroll
    for (int j = 0; j < 8; ++j) {
        float v0 = tile[(kb + j) * 65 + n], v1 = tile[(kb + 8 + j) * 65 + n];
        __bf16 hb0 = (__bf16)v0, hb1 = (__bf16)v1;
        h0[j] = hb0; h1[j] = hb1;
        if (SPLIT) { l0[j] = (__bf16)(v0 - (float)hb0); l1[j] = (__bf16)(v1 - (float)hb1); }
    }
    size_t o = (size_t)(n0 + n) * K + k0 + kb;
    *(bf16x8*)&oh[o] = h0; *(bf16x8*)&oh[o + 8] = h1;
    if (SPLIT) { *(bf16x8*)&ol[o] = l0; *(bf16x8*)&ol[o + 8] = l1; }
}

__global__ __launch_bounds__(256)
void prep(const float* __restrict__ x, const float* __restrict__ Wq,
          const float* __restrict__ Wkv, const float* __restrict__ Wv,
          const float* __restrict__ Wo, const float* __restrict__ Wk,
          const float* __restrict__ Wkr, const float* __restrict__ bk,
          __bf16* xh, __bf16* xl, __bf16* Wqt_h, __bf16* Wqt_l,
          __bf16* Wkvt_h, __bf16* Wkvt_l, __bf16* Wvt, __bf16* Wot,
          __bf16* W2th, __bf16* W2tl, float* b2)
{
    __shared__ float tile[64 * 65];
    const int g = blockIdx.x, tid = threadIdx.x;
    if (g < 2048) {                       // split x -> xh/xl
        size_t idx = ((size_t)g * 256 + tid) * 8;
        f32x4 a0 = *(const f32x4*)&x[idx];
        f32x4 a1 = *(const f32x4*)&x[idx + 4];
        bf16x8 h, l;
#pragma unroll
        for (int j = 0; j < 4; ++j) {
            __bf16 h0 = (__bf16)a0[j];
            h[j]     = h0; l[j]     = (__bf16)(a0[j] - (float)h0);
            __bf16 h1 = (__bf16)a1[j];
            h[4 + j] = h1; l[4 + j] = (__bf16)(a1[j] - (float)h1);
        }
        *(bf16x8*)&xh[idx] = h;
        *(bf16x8*)&xl[idx] = l;
    } else if (g < 2304) {                // Wq -> [N,K] split
        int i = g - 2048;
        tsplit_body(Wq, Wqt_h, Wqt_l, 1024, 1024, (i & 15) * 64, (i >> 4) * 64, 1, tile);
    } else if (g < 2368) {                // Wkv -> split
        int i = g - 2304;
        tsplit_body(Wkv, Wkvt_h, Wkvt_l, 1024, 256, (i & 3) * 64, (i >> 2) * 64, 1, tile);
    } else if (g < 2432) {                // Wv -> trunc
        int i = g - 2368;
        tsplit_body(Wv, Wvt, nullptr, 256, 1024, (i & 15) * 64, (i >> 4) * 64, 0, tile);
    } else if (g < 2688) {                // Wo -> trunc
        int i = g - 2432;
        tsplit_body(Wo, Wot, nullptr, 1024, 1024, (i & 15) * 64, (i >> 4) * 64, 0, tile);
    } else {                              // W2 = Wk_h @ Wkr (transposed split) + b2
        int o    = (g - 2688) * 256 + tid;
        int rowk = o >> 10, col = o & 1023;
        int h = col >> 6, d = col & 63;
        float acc = 0.0f;
        if (rowk < 256) {
#pragma unroll 8
            for (int j = 0; j < 64; ++j)
                acc += Wk[(size_t)rowk * DM + h * HD + j] * Wkr[j * HD + d];
            __bf16 hb = (__bf16)acc;
            W2th[(size_t)col * 256 + rowk] = hb;
            W2tl[(size_t)col * 256 + rowk] = (__bf16)(acc - (float)hb);
        } else {
#pragma unroll 8
            for (int j = 0; j < 64; ++j)
                acc += bk[h * HD + j] * Wkr[j * HD + d];
            b2[col] = acc;
        }
    }
}

// ================= 128x128 GEMM body =================
// A bf16 [M,K] (hi + optional lo), B bf16 [N,K] (hi + optional lo)
// OUTM: 0 bf16 | 1 fp32 | 2 dual split bf16
// EPI:  0 bias | 1 RoPE*QSCALE split-out | 2 bias then *t | 3 v->vtg transpose
// Staging: async global_load_lds width=16 (layout is wave-base + lane*16).
// NOTE: never pass nullptr for a lo pointer with DUAL*=1 (r5-r7 bug).
// NOTE: branches of ONE dispatch must never write memory another branch reads
// (r9 bug: v wrote vtg overlaying xlo read by q). q+kv / k+v merges are safe.
template <int DUALA, int DUALB, int OUTM, int EPI>
__device__ __forceinline__
void gemm_body(char* smem,
               const __bf16* __restrict__ Ahi, const __bf16* __restrict__ Alo,
               const __bf16* __restrict__ Bhi, const __bf16* __restrict__ Blo,
               const float* __restrict__ bias, void* __restrict__ Cp,
               void* __restrict__ Cp2, int m0, int n0, int N, int K)
{
    __bf16* Ah = (__bf16*)smem;               // [128][32]
    __bf16* Al = (__bf16*)(smem + 8192);
    __bf16* Bh = (__bf16*)(smem + 16384);     // [128][32] = [n][k]
    __bf16* Bl = (__bf16*)(smem + 24576);

    const int tid  = threadIdx.x;
    const int w    = tid >> 6;
    const int lane = tid & 63;
    const int l16  = lane & 15;
    const int quad = lane >> 4;
    const int wy   = w >> 1, wx = w & 1;

    f32x4 acc[4][4];
#pragma unroll
    for (int i = 0; i < 4; ++i)
#pragma unroll
        for (int j = 0; j < 4; ++j) acc[i][j] = (f32x4)0.0f;

    for (int k0 = 0; k0 < K; k0 += 32) {
        __syncthreads();
#pragma unroll
        for (int i = 0; i < 2; ++i) {
            int s = i * 256 + tid, row = s >> 2, c8 = (s & 3) * 8;
            gl2lds(&Ahi[(size_t)(m0 + row) * K + k0 + c8], &Ah[row * 32 + c8]);
            if (DUALA) gl2lds(&Alo[(size_t)(m0 + row) * K + k0 + c8], &Al[row * 32 + c8]);
            gl2lds(&Bhi[(size_t)(n0 + row) * K + k0 + c8], &Bh[row * 32 + c8]);
            if (DUALB) gl2lds(&Blo[(size_t)(n0 + row) * K + k0 + c8], &Bl[row * 32 + c8]);
        }
        __syncthreads();

        bf16x8 bfh[4], bfl[4];
#pragma unroll
        for (int ct = 0; ct < 4; ++ct) {
            bfh[ct] = *(const bf16x8*)&Bh[(wx * 64 + ct * 16 + l16) * 32 + quad * 8];
            if (DUALB) bfl[ct] = *(const bf16x8*)&Bl[(wx * 64 + ct * 16 + l16) * 32 + quad * 8];
        }
#pragma unroll
        for (int mf = 0; mf < 4; ++mf) {
            bf16x8 ah = *(const bf16x8*)&Ah[(wy * 64 + mf * 16 + l16) * 32 + quad * 8];
            bf16x8 al;
            if (DUALA) al = *(const bf16x8*)&Al[(wy * 64 + mf * 16 + l16) * 32 + quad * 8];
#pragma unroll
            for (int ct = 0; ct < 4; ++ct) {
                acc[mf][ct] = mfma16(ah, bfh[ct], acc[mf][ct]);
                if (DUALA) acc[mf][ct] = mfma16(al, bfh[ct], acc[mf][ct]);
                if (DUALB) acc[mf][ct] = mfma16(ah, bfl[ct], acc[mf][ct]);
            }
        }
    }

    float bias_v[4];
#pragma unroll
    for (int ct = 0; ct < 4; ++ct)
        bias_v[ct] = bias ? bias[n0 + wx * 64 + ct * 16 + l16] : 0.0f;

    if (EPI == 1) {  // RoPE (q): pair (d, d+32) = (ct, ct+2); *QSCALE; split out
        __bf16* Chi = (__bf16*)Cp;
        __bf16* Clo = (__bf16*)Cp2;
#pragma unroll
        for (int mf = 0; mf < 4; ++mf) {
#pragma unroll
            for (int r = 0; r < 4; ++r) {
                int   m = m0 + wy * 64 + mf * 16 + quad * 4 + r;
                float t = (float)(m & (T_SEQ - 1));
#pragma unroll
                for (int ct = 0; ct < 2; ++ct) {
                    int   d   = ct * 16 + l16;
                    float inv = powf(10000.0f, -(float)d * (1.0f / 32.0f));
                    float sv, cv;
                    sincosf(t * inv, &sv, &cv);
                    float lo = acc[mf][ct][r]     + bias_v[ct];
                    float hi = acc[mf][ct + 2][r] + bias_v[ct + 2];
                    float v0 = (lo * cv - hi * sv) * QSCALE;
                    float v1 = (hi * cv + lo * sv) * QSCALE;
                    size_t i0 = (size_t)m * N + n0 + wx * 64 + d;
                    size_t i1 = i0 + 32;
                    __bf16 h0 = (__bf16)v0, h1 = (__bf16)v1;
                    Chi[i0] = h0; Clo[i0] = (__bf16)(v0 - (float)h0);
                    Chi[i1] = h1; Clo[i1] = (__bf16)(v1 - (float)h1);
                }
            }
        }
    } else if (EPI == 3) {  // v: write vtg[bh][d][t] via per-wave LDS transpose
        __syncthreads();
        __bf16* vt = (__bf16*)(smem + w * 9216);   // [64][72]
#pragma unroll
        for (int mf = 0; mf < 4; ++mf)
#pragma unroll
            for (int ct = 0; ct < 4; ++ct)
#pragma unroll
                for (int r = 0; r < 4; ++r)
                    vt[(ct * 16 + l16) * 72 + mf * 16 + quad * 4 + r] =
                        (__bf16)(acc[mf][ct][r] + bias_v[ct]);
        const int bb   = m0 >> 11;
        const int head = (n0 + wx * 64) >> 6;
        const int bh   = bb * 16 + head;
        __bf16* out    = (__bf16*)Cp;
        size_t  gbase  = ((size_t)(bh * 64 + lane)) * T_SEQ + (m0 & (T_SEQ - 1)) + wy * 64;
#pragma unroll
        for (int j8 = 0; j8 < 8; ++j8)
            *(bf16x8*)&out[gbase + j8 * 8] = *(const bf16x8*)&vt[lane * 72 + j8 * 8];
    } else {
#pragma unroll
        for (int mf = 0; mf < 4; ++mf) {
#pragma unroll
            for (int r = 0; r < 4; ++r) {
                int   m     = m0 + wy * 64 + mf * 16 + quad * 4 + r;
                float scale = (EPI == 2) ? (float)(m & (T_SEQ - 1)) : 1.0f;
#pragma unroll
                for (int ct = 0; ct < 4; ++ct) {
                    float  v   = (acc[mf][ct][r] + bias_v[ct]) * scale;
                    size_t idx = (size_t)m * N + n0 + wx * 64 + ct * 16 + l16;
                    if (OUTM == 1)      ((float*)Cp)[idx]  = v;
                    else if (OUTM == 0) ((__bf16*)Cp)[idx] = (__bf16)v;
                    else {
                        __bf16 hb = (__bf16)v;
                        ((__bf16*)Cp)[idx]  = hb;
                        ((__bf16*)Cp2)[idx] = (__bf16)(v - (float)hb);
                    }
                }
            }
        }
    }
}

// merged kv + q gemm: grid (10, 32) = 320 blocks (kv first so it fills early)
__global__ __launch_bounds__(256)
void gemm_qkv(const __bf16* xh, const __bf16* xl,
              const __bf16* Wqt_h, const __bf16* Wqt_l, const float* bq,
              __bf16* qhi, __bf16* qlo,
              const __bf16* Wkvt_h, const __bf16* Wkvt_l, const float* bkv,
              __bf16* kvhi, __bf16* kvlo)
{
    __shared__ __attribute__((aligned(16))) char smem[36864];
    const int m0 = blockIdx.y * 128;
    if (blockIdx.x < 2)
        gemm_body<1, 1, 2, 0>(smem, xh, xl, Wkvt_h, Wkvt_l, bkv, kvhi, kvlo,
                              m0, blockIdx.x * 128, 256, 1024);
    else
        gemm_body<1, 1, 2, 1>(smem, xh, xl, Wqt_h, Wqt_l, bq, qhi, qlo,
                              m0, (blockIdx.x - 2) * 128, 1024, 1024);
}

// merged k + v gemm: grid (16, 32) = 512 blocks. Safe merge: v writes vtg
// (overlays xlo) and no branch here reads xlo (q is in the previous dispatch).
__global__ __launch_bounds__(256)
void gemm_kv2(const __bf16* kvhi, const __bf16* kvlo,
              const __bf16* W2th, const __bf16* W2tl, const float* b2,
              __bf16* khi, __bf16* klo,
              const __bf16* Wvt, const float* bv, __bf16* vtg)
{
    __shared__ __attribute__((aligned(16))) char smem[36864];
    const int m0 = blockIdx.y * 128;
    if (blockIdx.x < 8)
        gemm_body<1, 1, 2, 2>(smem, kvhi, kvlo, W2th, W2tl, b2, khi, klo,
                              m0, blockIdx.x * 128, 1024, 256);
    else
        gemm_body<1, 0, 0, 3>(smem, kvhi, kvlo, Wvt, Wvt, bv, vtg, nullptr,
                              m0, (blockIdx.x - 8) * 128, 1024, 256);
}

// o gemm: grid (8, 32)
__global__ __launch_bounds__(256)
void gemm_o(const __bf16* ybb, const __bf16* Wot, const float* bo, float* out)
{
    __shared__ __attribute__((aligned(16))) char smem[36864];
    gemm_body<0, 0, 1, 0>(smem, ybb, ybb, Wot, Wot, bo, out, nullptr,
                          blockIdx.y * 128, blockIdx.x * 128, 1024, 1024);
}

// ================= flash attention v6b =================
// Transposed dataflow (S^T = K Q^T, O^T = V^T P^T), cross-quad shfl row
// reductions, 16B-aligned P rows, single-buffered K/V + register prefetch +
// 2 barriers/step + ONE shared per-wave P buffer -> LDS 36.9 KB.
// __launch_bounds__(256, 3): r11's (256,4) capped VGPR at 64 -> ~84 MB scratch
// spills/dispatch (WRITE_SIZE 8->92 MB), 205 µs. At 3 waves/EU the cap is
// ~170 VGPR (kernel needs ~120) -> no spills, still 3 blocks/CU (12 waves/CU,
// 1.5x v5's 8).
#define KSP 72
#define PSP 72
__global__ __launch_bounds__(256, 3)
void attn_v6(const __bf16* __restrict__ qhi, const __bf16* __restrict__ qlo,
             const __bf16* __restrict__ khi, const __bf16* __restrict__ klo,
             const __bf16* __restrict__ vtg, __bf16* __restrict__ yb)
{
    __shared__ __attribute__((aligned(16))) __bf16 Kh[64 * KSP];
    __shared__ __attribute__((aligned(16))) __bf16 Kl[64 * KSP];
    __shared__ __attribute__((aligned(16))) __bf16 Vt[64 * KSP];   // [d][key]
    __shared__ __attribute__((aligned(16))) __bf16 Pw[4][16 * PSP]; // per-wave [qrow][key]

    const int tid  = threadIdx.x;
    const int w    = tid >> 6;
    const int lane = tid & 63;
    const int l16  = lane & 15;
    const int quad = lane >> 4;

    // bh = g&31 (XCD-stable); tiles paired (15-2a, 2(a-8)) so co-resident pairs sum to 34 steps
    const int g  = blockIdx.x;
    const int bh = g & 31, a = g >> 5;
    const int tile = (a < 8) ? (15 - 2 * a) : (2 * (a - 8));
    const int b = bh >> 4, h = bh & 15;
    const int q0 = tile * 128;

    // Q B-frags (pre-scaled by QSCALE), 2 frags x 2 k-halves
    bf16x8 qh[2][2], ql[2][2];
#pragma unroll
    for (int f = 0; f < 2; ++f) {
        const int    qrow = q0 + 64 * f + 16 * w + l16;
        const size_t qoff = (size_t)(b * T_SEQ + qrow) * DM + h * HD;
#pragma unroll
        for (int s = 0; s < 2; ++s) {
            qh[f][s] = *(const bf16x8*)&qhi[qoff + s * 32 + quad * 8];
            ql[f][s] = *(const bf16x8*)&qlo[qoff + s * 32 + quad * 8];
        }
    }

    f32x4 o[2][4];
#pragma unroll
    for (int f = 0; f < 2; ++f)
#pragma unroll
        for (int i = 0; i < 4; ++i) o[f][i] = (f32x4)0.0f;
    float m_i[2] = {-1e30f, -1e30f}, l_i[2] = {0.f, 0.f};

    const int srow = tid >> 3, sc8 = (tid & 7) * 8;
    bf16x8 kr[2], lr[2], vr[2];
    __bf16* pw = &Pw[w][0];

    // prologue: load step 0 into regs, commit to LDS (barrier1 publishes it)
#pragma unroll
    for (int it = 0; it < 2; ++it) {
        int    r  = it * 32 + srow;
        size_t gk = (size_t)(b * T_SEQ + r) * DM + h * HD + sc8;
        kr[it] = *(const bf16x8*)&khi[gk];
        lr[it] = *(const bf16x8*)&klo[gk];
        vr[it] = *(const bf16x8*)&vtg[(size_t)(bh * HD + r) * T_SEQ + sc8];
    }
#pragma unroll
    for (int it = 0; it < 2; ++it) {
        int r = it * 32 + srow;
        *(bf16x8*)&Kh[r * KSP + sc8] = kr[it];
        *(bf16x8*)&Kl[r * KSP + sc8] = lr[it];
        *(bf16x8*)&Vt[r * KSP + sc8] = vr[it];
    }

    const int jmax = q0 + 64;
    for (int j0 = 0; j0 <= jmax; j0 += 64) {
        const bool act0 = (j0 <= q0);   // frag0 fully masked on final step
        const bool pre  = (j0 + 64 <= jmax);
        __syncthreads();                // barrier1: commits of step j-1 visible

        // issue next step's global loads (latency overlaps all compute below)
        if (pre) {
#pragma unroll
            for (int it = 0; it < 2; ++it) {
                int    r  = it * 32 + srow;
                size_t gk = (size_t)(b * T_SEQ + j0 + 64 + r) * DM + h * HD + sc8;
                kr[it] = *(const bf16x8*)&khi[gk];
                lr[it] = *(const bf16x8*)&klo[gk];
                vr[it] = *(const bf16x8*)&vtg[(size_t)(bh * HD + r) * T_SEQ + j0 + 64 + sc8];
            }
        }

        // S^T = K Q^T: rows=keys (kc,quad,reg), cols=qrows (l16)
        f32x4 sa[2][4];
#pragma unroll
        for (int f = 0; f < 2; ++f)
#pragma unroll
            for (int i = 0; i < 4; ++i) sa[f][i] = (f32x4)0.0f;
#pragma unroll
        for (int s = 0; s < 2; ++s) {
#pragma unroll
            for (int kc = 0; kc < 4; ++kc) {
                bf16x8 kh = *(const bf16x8*)&Kh[(kc * 16 + l16) * KSP + s * 32 + quad * 8];
                bf16x8 kv = *(const bf16x8*)&Kl[(kc * 16 + l16) * KSP + s * 32 + quad * 8];
                sa[1][kc] = mfma16(kh, qh[1][s], sa[1][kc]);
                sa[1][kc] = mfma16(kv, qh[1][s], sa[1][kc]);
                sa[1][kc] = mfma16(kh, ql[1][s], sa[1][kc]);
                if (act0) {
                    sa[0][kc] = mfma16(kh, qh[0][s], sa[0][kc]);
                    sa[0][kc] = mfma16(kv, qh[0][s], sa[0][kc]);
                    sa[0][kc] = mfma16(kh, ql[0][s], sa[0][kc]);
                }
            }
        }

        // per-frag: online softmax (cross-quad shfl_xor(16,32) row reductions,
        // r5 NaN fix) then immediately P->LDS + PV, sharing ONE per-wave pw
#pragma unroll
        for (int f = 0; f < 2; ++f) {
            if (f == 0 && !act0) continue;
            const int  qrow = q0 + 64 * f + 16 * w + l16;
            const bool need = (j0 + 63 > q0 + 64 * f + 16 * w);
            if (need) {
#pragma unroll
                for (int kc = 0; kc < 4; ++kc)
#pragma unroll
                    for (int r = 0; r < 4; ++r)
                        if (j0 + kc * 16 + quad * 4 + r > qrow) sa[f][kc][r] = -1e30f;
            }
            float mx = -1e30f;
#pragma unroll
            for (int kc = 0; kc < 4; ++kc)
#pragma unroll
                for (int r = 0; r < 4; ++r) mx = fmaxf(mx, sa[f][kc][r]);
            mx = fmaxf(mx, __shfl_xor(mx, 16));
            mx = fmaxf(mx, __shfl_xor(mx, 32));
            float mn    = fmaxf(fmaxf(m_i[f], mx), -1e20f);
            float alpha = exp2f(m_i[f] - mn);
            m_i[f] = mn;
            float rs = 0.f;
#pragma unroll
            for (int kc = 0; kc < 4; ++kc) {
                float p0 = exp2f(sa[f][kc][0] - mn);
                float p1 = exp2f(sa[f][kc][1] - mn);
                float p2 = exp2f(sa[f][kc][2] - mn);
                float p3 = exp2f(sa[f][kc][3] - mn);
                rs += (p0 + p1) + (p2 + p3);
                bf16x4 pk = { (__bf16)p0, (__bf16)p1, (__bf16)p2, (__bf16)p3 };
                *(bf16x4*)&pw[l16 * PSP + kc * 16 + quad * 4] = pk;
            }
            rs += __shfl_xor(rs, 16);
            rs += __shfl_xor(rs, 32);
            l_i[f] = l_i[f] * alpha + rs;
#pragma unroll
            for (int dc = 0; dc < 4; ++dc) o[f][dc] *= alpha;

            // O^T += V^T P^T for this frag (pw is per-wave: no block sync)
#pragma unroll
            for (int s = 0; s < 2; ++s) {
                bf16x8 pb = *(const bf16x8*)&pw[l16 * PSP + s * 32 + quad * 8];
#pragma unroll
                for (int dc = 0; dc < 4; ++dc) {
                    bf16x8 va = *(const bf16x8*)&Vt[(dc * 16 + l16) * KSP + s * 32 + quad * 8];
                    o[f][dc] = mfma16(va, pb, o[f][dc]);
                }
            }
        }

        __syncthreads();                // barrier2: all waves done reading K/V
        if (pre) {
#pragma unroll
            for (int it = 0; it < 2; ++it) {
                int r = it * 32 + srow;
                *(bf16x8*)&Kh[r * KSP + sc8] = kr[it];
                *(bf16x8*)&Kl[r * KSP + sc8] = lr[it];
                *(bf16x8*)&Vt[r * KSP + sc8] = vr[it];
            }
        }
    }

    // epilogue: normalize, transpose via per-wave pw, coalesced store
#pragma unroll
    for (int f = 0; f < 2; ++f) {
        float invl = 1.0f / l_i[f];
#pragma unroll
        for (int dc = 0; dc < 4; ++dc) {
            bf16x4 ov = { (__bf16)(o[f][dc][0] * invl), (__bf16)(o[f][dc][1] * invl),
                          (__bf16)(o[f][dc][2] * invl), (__bf16)(o[f][dc][3] * invl) };
            *(bf16x4*)&pw[l16 * PSP + dc * 16 + quad * 4] = ov;
        }
        const int qrl  = lane >> 2;          // 0..15
        const int dch  = (lane & 3) * 16;    // 0,16,32,48
        const int qrow = q0 + 64 * f + 16 * w + qrl;
        const __bf16* src = &pw[qrl * PSP + dch];
        __bf16*       dst = &yb[(size_t)(b * T_SEQ + qrow) * DM + h * HD + dch];
        *(bf16x8*)dst       = *(const bf16x8*)src;
        *(bf16x8*)(dst + 8) = *(const bf16x8*)(src + 8);
    }
}

extern "C" void kernel_launch(void* const* d_in, const int* in_sizes, int n_in,
                              void* d_out, int out_size, void* d_ws, size_t ws_size,
                              hipStream_t stream)
{
    (void)in_sizes; (void)n_in; (void)out_size; (void)ws_size;

    const float* x   = (const float*)d_in[0];
    const float* Wq  = (const float*)d_in[2];
    const float* bq  = (const float*)d_in[3];
    const float* Wkv = (const float*)d_in[4];
    const float* bkv = (const float*)d_in[5];
    const float* Wk  = (const float*)d_in[6];
    const float* bk  = (const float*)d_in[7];
    const float* Wv  = (const float*)d_in[8];
    const float* bv  = (const float*)d_in[9];
    const float* Wo  = (const float*)d_in[10];
    const float* bo  = (const float*)d_in[11];
    const float* Wkr = (const float*)d_in[12];

    const int    BT = 2 * T_SEQ;   // 4096
    const size_t MB = 1024 * 1024;
    char* base = (char*)d_ws;

    __bf16* xhi    = (__bf16*)(base +  0 * MB);
    __bf16* xlo    = (__bf16*)(base +  8 * MB);
    __bf16* qhi    = (__bf16*)(base + 16 * MB);
    __bf16* qlo    = (__bf16*)(base + 24 * MB);
    __bf16* Wqt_h  = (__bf16*)(base + 32 * MB);
    __bf16* Wqt_l  = (__bf16*)(base + 34 * MB);
    __bf16* Wkvt_h = (__bf16*)(base + 36 * MB);
    __bf16* Wkvt_l = (__bf16*)(base + 37 * MB);
    __bf16* kvhi   = (__bf16*)(base + 38 * MB);
    __bf16* kvlo   = (__bf16*)(base + 40 * MB);
    __bf16* W2t_h  = (__bf16*)(base + 42 * MB);
    __bf16* W2t_l  = (__bf16*)(base + 42 * MB + 512 * 1024);
    __bf16* Wvt    = (__bf16*)(base + 43 * MB);
    __bf16* Wot    = (__bf16*)(base + 43 * MB + 512 * 1024);
    float*  b2     = (float*) (base + 45 * MB + 512 * 1024);
    __bf16* vtg    = (__bf16*)(base +  8 * MB);               // overlays xlo (dead after gemm_qkv)
    __bf16* ybb    = (__bf16*)(base +  0 * MB);               // overlays xhi (dead after gemm_qkv)
    __bf16* khi    = (__bf16*)d_out;                          // d_out as scratch
    __bf16* klo    = (__bf16*)d_out + (size_t)BT * DM;        // overwritten by o gemm

    dim3 blk(256);
    prep<<<3716, blk, 0, stream>>>(x, Wq, Wkv, Wv, Wo, Wk, Wkr, bk,
                                   xhi, xlo, Wqt_h, Wqt_l, Wkvt_h, Wkvt_l,
                                   Wvt, Wot, W2t_h, W2t_l, b2);
    gemm_qkv<<<dim3(10, 32), blk, 0, stream>>>(xhi, xlo, Wqt_h, Wqt_l, bq, qhi, qlo,
                                               Wkvt_h, Wkvt_l, bkv, kvhi, kvlo);
    gemm_kv2<<<dim3(16, 32), blk, 0, stream>>>(kvhi, kvlo, W2t_h, W2t_l, b2,
                                               khi, klo, Wvt, bv, vtg);
    attn_v6<<<512, blk, 0, stream>>>(qhi, qlo, khi, klo, vtg, ybb);
    gemm_o<<<dim3(8, 32), blk, 0, stream>>>(ybb, Wot, bo, (float*)d_out);
}

// Round 13
// 279.798 us; speedup vs baseline: 1.4450x; 1.0746x over previous
//
#include <hip/hip_runtime.h>
#include <hip/hip_bf16.h>
#include <math.h>

typedef __bf16 bf16x8 __attribute__((ext_vector_type(8)));
typedef __bf16 bf16x4 __attribute__((ext_vector_type(4)));
typedef float  f32x4  __attribute__((ext_vector_type(4)));

#define T_SEQ 2048
#define NH    16
#define HD    64
#define DM    1024
// softmax logits pre-scaled by 1/sqrt(64) * log2(e) so we can use exp2
#define QSCALE 0.18033688011112043f

__device__ __forceinline__ f32x4 mfma16(bf16x8 a, bf16x8 b, f32x4 c) {
    return __builtin_amdgcn_mfma_f32_16x16x32_bf16(a, b, c, 0, 0, 0);
}

// async global->LDS, 16B per lane. LDS dest is wave-uniform base + lane*16
// (our staging layout is exactly that). Barrier's implicit vmcnt(0) drains.
__device__ __forceinline__ void gl2lds(const void* g, void* l) {
    __builtin_amdgcn_global_load_lds(
        (const __attribute__((address_space(1))) void*)g,
        (__attribute__((address_space(3))) void*)l, 16, 0, 0);
}

// ================= prep (one dispatch) =================
__device__ __forceinline__ void tsplit_body(const float* __restrict__ in,
                                            __bf16* __restrict__ oh, __bf16* __restrict__ ol,
                                            int K, int N, int n0, int k0, int SPLIT,
                                            float* tile /* [64][65] LDS */)
{
    const int tid = threadIdx.x;
#pragma unroll
    for (int it = 0; it < 2; ++it) {
        int r = it * 32 + (tid >> 3), c8 = (tid & 7) * 8;
        f32x4 a0 = *(const f32x4*)&in[(size_t)(k0 + r) * N + n0 + c8];
        f32x4 a1 = *(const f32x4*)&in[(size_t)(k0 + r) * N + n0 + c8 + 4];
#pragma unroll
        for (int j = 0; j < 4; ++j) { tile[r * 65 + c8 + j] = a0[j]; tile[r * 65 + c8 + 4 + j] = a1[j]; }
    }
    __syncthreads();
    const int n = tid >> 2, kb = (tid & 3) * 16;
    bf16x8 h0, h1, l0, l1;
#pragma unroll
    for (int j = 0; j < 8; ++j) {
        float v0 = tile[(kb + j) * 65 + n], v1 = tile[(kb + 8 + j) * 65 + n];
        __bf16 hb0 = (__bf16)v0, hb1 = (__bf16)v1;
        h0[j] = hb0; h1[j] = hb1;
        if (SPLIT) { l0[j] = (__bf16)(v0 - (float)hb0); l1[j] = (__bf16)(v1 - (float)hb1); }
    }
    size_t o = (size_t)(n0 + n) * K + k0 + kb;
    *(bf16x8*)&oh[o] = h0; *(bf16x8*)&oh[o + 8] = h1;
    if (SPLIT) { *(bf16x8*)&ol[o] = l0; *(bf16x8*)&ol[o + 8] = l1; }
}

__global__ __launch_bounds__(256)
void prep(const float* __restrict__ x, const float* __restrict__ Wq,
          const float* __restrict__ Wkv, const float* __restrict__ Wv,
          const float* __restrict__ Wo, const float* __restrict__ Wk,
          const float* __restrict__ Wkr, const float* __restrict__ bk,
          __bf16* xh, __bf16* xl, __bf16* Wqt_h, __bf16* Wqt_l,
          __bf16* Wkvt_h, __bf16* Wkvt_l, __bf16* Wvt, __bf16* Wot,
          __bf16* W2th, __bf16* W2tl, float* b2)
{
    __shared__ float tile[64 * 65];
    const int g = blockIdx.x, tid = threadIdx.x;
    if (g < 2048) {                       // split x -> xh/xl
        size_t idx = ((size_t)g * 256 + tid) * 8;
        f32x4 a0 = *(const f32x4*)&x[idx];
        f32x4 a1 = *(const f32x4*)&x[idx + 4];
        bf16x8 h, l;
#pragma unroll
        for (int j = 0; j < 4; ++j) {
            __bf16 h0 = (__bf16)a0[j];
            h[j]     = h0; l[j]     = (__bf16)(a0[j] - (float)h0);
            __bf16 h1 = (__bf16)a1[j];
            h[4 + j] = h1; l[4 + j] = (__bf16)(a1[j] - (float)h1);
        }
        *(bf16x8*)&xh[idx] = h;
        *(bf16x8*)&xl[idx] = l;
    } else if (g < 2304) {                // Wq -> [N,K] split
        int i = g - 2048;
        tsplit_body(Wq, Wqt_h, Wqt_l, 1024, 1024, (i & 15) * 64, (i >> 4) * 64, 1, tile);
    } else if (g < 2368) {                // Wkv -> split
        int i = g - 2304;
        tsplit_body(Wkv, Wkvt_h, Wkvt_l, 1024, 256, (i & 3) * 64, (i >> 2) * 64, 1, tile);
    } else if (g < 2432) {                // Wv -> trunc
        int i = g - 2368;
        tsplit_body(Wv, Wvt, nullptr, 256, 1024, (i & 15) * 64, (i >> 4) * 64, 0, tile);
    } else if (g < 2688) {                // Wo -> trunc
        int i = g - 2432;
        tsplit_body(Wo, Wot, nullptr, 1024, 1024, (i & 15) * 64, (i >> 4) * 64, 0, tile);
    } else {                              // W2 = Wk_h @ Wkr (transposed split) + b2
        int o    = (g - 2688) * 256 + tid;
        int rowk = o >> 10, col = o & 1023;
        int h = col >> 6, d = col & 63;
        float acc = 0.0f;
        if (rowk < 256) {
#pragma unroll 8
            for (int j = 0; j < 64; ++j)
                acc += Wk[(size_t)rowk * DM + h * HD + j] * Wkr[j * HD + d];
            __bf16 hb = (__bf16)acc;
            W2th[(size_t)col * 256 + rowk] = hb;
            W2tl[(size_t)col * 256 + rowk] = (__bf16)(acc - (float)hb);
        } else {
#pragma unroll 8
            for (int j = 0; j < 64; ++j)
                acc += bk[h * HD + j] * Wkr[j * HD + d];
            b2[col] = acc;
        }
    }
}

// ================= 128x128-tile GEMM, async-pipelined K-loop =================
// A bf16 [M,K] (hi + optional lo), B bf16 [N,K] (hi + optional lo)
// OUTM: 0 bf16 | 1 fp32 | 2 dual split bf16
// EPI:  0 bias | 1 RoPE*QSCALE split-out | 2 bias then *t | 3 v->vtg transpose
// K-loop: DOUBLE-BUFFERED gl2lds panels, ONE barrier per 32-K step:
//   barrier; issue gl2lds(step j+1 -> buf^1); compute(buf)
// so the loads for j+1 overlap compute of j and are drained at the NEXT
// barrier (r12 structure drained them immediately with nothing overlapped —
// a naked ~200-900 cyc latency per step at 1.25-2 blocks/CU).
// LDS layout per buf (32768 B): Ah @0, Al @8192, Bh @16384, Bl @24576.
// NOTE: never pass nullptr for a lo pointer with DUAL*=1 (r5-r7 bug).
// NOTE: branches of ONE dispatch must never write memory another branch reads
// (r9 bug: v wrote vtg overlaying xlo read by q). q+kv / k+v merges are safe.
template <int DUALA, int DUALB, int OUTM, int EPI>
__device__ __forceinline__
void gemm_body(char* smem,
               const __bf16* __restrict__ Ahi, const __bf16* __restrict__ Alo,
               const __bf16* __restrict__ Bhi, const __bf16* __restrict__ Blo,
               const float* __restrict__ bias, void* __restrict__ Cp,
               void* __restrict__ Cp2, int m0, int n0, int N, int K)
{
    const int tid  = threadIdx.x;
    const int w    = tid >> 6;
    const int lane = tid & 63;
    const int l16  = lane & 15;
    const int quad = lane >> 4;
    const int wy   = w >> 1, wx = w & 1;

    f32x4 acc[4][4];
#pragma unroll
    for (int i = 0; i < 4; ++i)
#pragma unroll
        for (int j = 0; j < 4; ++j) acc[i][j] = (f32x4)0.0f;

    auto stage = [&](int k0, int buf) {
        char* bb = smem + buf * 32768;
#pragma unroll
        for (int i = 0; i < 2; ++i) {
            int s = i * 256 + tid, row = s >> 2, c8 = (s & 3) * 8;
            size_t aoff = (size_t)(m0 + row) * K + k0 + c8;
            size_t boff = (size_t)(n0 + row) * K + k0 + c8;
            char*  dst  = bb + (row * 32 + c8) * 2;
            gl2lds(&Ahi[aoff], dst);
            if (DUALA) gl2lds(&Alo[aoff], dst + 8192);
            gl2lds(&Bhi[boff], dst + 16384);
            if (DUALB) gl2lds(&Blo[boff], dst + 24576);
        }
    };

    stage(0, 0);
    const int J = K >> 5;
    for (int j = 0; j < J; ++j) {
        __syncthreads();               // drains gl2lds for step j (all waves)
        if (j + 1 < J) stage((j + 1) << 5, (j + 1) & 1);   // overlaps compute

        const __bf16* Ah = (const __bf16*)(smem + (j & 1) * 32768);
        const __bf16* Al = Ah + 4096;
        const __bf16* Bh = Ah + 8192;
        const __bf16* Bl = Ah + 12288;

        bf16x8 bfh[4], bfl[4];
#pragma unroll
        for (int ct = 0; ct < 4; ++ct) {
            bfh[ct] = *(const bf16x8*)&Bh[(wx * 64 + ct * 16 + l16) * 32 + quad * 8];
            if (DUALB) bfl[ct] = *(const bf16x8*)&Bl[(wx * 64 + ct * 16 + l16) * 32 + quad * 8];
        }
#pragma unroll
        for (int mf = 0; mf < 4; ++mf) {
            bf16x8 ah = *(const bf16x8*)&Ah[(wy * 64 + mf * 16 + l16) * 32 + quad * 8];
            bf16x8 al;
            if (DUALA) al = *(const bf16x8*)&Al[(wy * 64 + mf * 16 + l16) * 32 + quad * 8];
#pragma unroll
            for (int ct = 0; ct < 4; ++ct) {
                acc[mf][ct] = mfma16(ah, bfh[ct], acc[mf][ct]);
                if (DUALA) acc[mf][ct] = mfma16(al, bfh[ct], acc[mf][ct]);
                if (DUALB) acc[mf][ct] = mfma16(ah, bfl[ct], acc[mf][ct]);
            }
        }
    }

    float bias_v[4];
#pragma unroll
    for (int ct = 0; ct < 4; ++ct)
        bias_v[ct] = bias ? bias[n0 + wx * 64 + ct * 16 + l16] : 0.0f;

    if (EPI == 1) {  // RoPE (q): pair (d, d+32) = (ct, ct+2); *QSCALE; split out
        __bf16* Chi = (__bf16*)Cp;
        __bf16* Clo = (__bf16*)Cp2;
#pragma unroll
        for (int mf = 0; mf < 4; ++mf) {
#pragma unroll
            for (int r = 0; r < 4; ++r) {
                int   m = m0 + wy * 64 + mf * 16 + quad * 4 + r;
                float t = (float)(m & (T_SEQ - 1));
#pragma unroll
                for (int ct = 0; ct < 2; ++ct) {
                    int   d   = ct * 16 + l16;
                    float inv = powf(10000.0f, -(float)d * (1.0f / 32.0f));
                    float sv, cv;
                    sincosf(t * inv, &sv, &cv);
                    float lo = acc[mf][ct][r]     + bias_v[ct];
                    float hi = acc[mf][ct + 2][r] + bias_v[ct + 2];
                    float v0 = (lo * cv - hi * sv) * QSCALE;
                    float v1 = (hi * cv + lo * sv) * QSCALE;
                    size_t i0 = (size_t)m * N + n0 + wx * 64 + d;
                    size_t i1 = i0 + 32;
                    __bf16 h0 = (__bf16)v0, h1 = (__bf16)v1;
                    Chi[i0] = h0; Clo[i0] = (__bf16)(v0 - (float)h0);
                    Chi[i1] = h1; Clo[i1] = (__bf16)(v1 - (float)h1);
                }
            }
        }
    } else if (EPI == 3) {  // v: write vtg[bh][d][t] via per-wave LDS transpose
        __syncthreads();
        __bf16* vt = (__bf16*)(smem + w * 9216);   // [64][72]
#pragma unroll
        for (int mf = 0; mf < 4; ++mf)
#pragma unroll
            for (int ct = 0; ct < 4; ++ct)
#pragma unroll
                for (int r = 0; r < 4; ++r)
                    vt[(ct * 16 + l16) * 72 + mf * 16 + quad * 4 + r] =
                        (__bf16)(acc[mf][ct][r] + bias_v[ct]);
        const int bb   = m0 >> 11;
        const int head = (n0 + wx * 64) >> 6;
        const int bh   = bb * 16 + head;
        __bf16* out    = (__bf16*)Cp;
        size_t  gbase  = ((size_t)(bh * 64 + lane)) * T_SEQ + (m0 & (T_SEQ - 1)) + wy * 64;
#pragma unroll
        for (int j8 = 0; j8 < 8; ++j8)
            *(bf16x8*)&out[gbase + j8 * 8] = *(const bf16x8*)&vt[lane * 72 + j8 * 8];
    } else {
#pragma unroll
        for (int mf = 0; mf < 4; ++mf) {
#pragma unroll
            for (int r = 0; r < 4; ++r) {
                int   m     = m0 + wy * 64 + mf * 16 + quad * 4 + r;
                float scale = (EPI == 2) ? (float)(m & (T_SEQ - 1)) : 1.0f;
#pragma unroll
                for (int ct = 0; ct < 4; ++ct) {
                    float  v   = (acc[mf][ct][r] + bias_v[ct]) * scale;
                    size_t idx = (size_t)m * N + n0 + wx * 64 + ct * 16 + l16;
                    if (OUTM == 1)      ((float*)Cp)[idx]  = v;
                    else if (OUTM == 0) ((__bf16*)Cp)[idx] = (__bf16)v;
                    else {
                        __bf16 hb = (__bf16)v;
                        ((__bf16*)Cp)[idx]  = hb;
                        ((__bf16*)Cp2)[idx] = (__bf16)(v - (float)hb);
                    }
                }
            }
        }
    }
}

// merged kv + q gemm: grid (10, 32) = 320 blocks (kv first so it fills early)
__global__ __launch_bounds__(256)
void gemm_qkv(const __bf16* xh, const __bf16* xl,
              const __bf16* Wqt_h, const __bf16* Wqt_l, const float* bq,
              __bf16* qhi, __bf16* qlo,
              const __bf16* Wkvt_h, const __bf16* Wkvt_l, const float* bkv,
              __bf16* kvhi, __bf16* kvlo)
{
    __shared__ __attribute__((aligned(16))) char smem[65536];
    const int m0 = blockIdx.y * 128;
    if (blockIdx.x < 2)
        gemm_body<1, 1, 2, 0>(smem, xh, xl, Wkvt_h, Wkvt_l, bkv, kvhi, kvlo,
                              m0, blockIdx.x * 128, 256, 1024);
    else
        gemm_body<1, 1, 2, 1>(smem, xh, xl, Wqt_h, Wqt_l, bq, qhi, qlo,
                              m0, (blockIdx.x - 2) * 128, 1024, 1024);
}

// merged k + v gemm: grid (16, 32) = 512 blocks = 2/CU. Safe merge: v writes
// vtg (overlays xlo) and no branch here reads xlo (q is in the prior dispatch).
__global__ __launch_bounds__(256)
void gemm_kv2(const __bf16* kvhi, const __bf16* kvlo,
              const __bf16* W2th, const __bf16* W2tl, const float* b2,
              __bf16* khi, __bf16* klo,
              const __bf16* Wvt, const float* bv, __bf16* vtg)
{
    __shared__ __attribute__((aligned(16))) char smem[65536];
    const int m0 = blockIdx.y * 128;
    if (blockIdx.x < 8)
        gemm_body<1, 1, 2, 2>(smem, kvhi, kvlo, W2th, W2tl, b2, khi, klo,
                              m0, blockIdx.x * 128, 1024, 256);
    else
        gemm_body<1, 0, 0, 3>(smem, kvhi, kvlo, Wvt, Wvt, bv, vtg, nullptr,
                              m0, (blockIdx.x - 8) * 128, 1024, 256);
}

// o gemm: grid (8, 32)
__global__ __launch_bounds__(256)
void gemm_o(const __bf16* ybb, const __bf16* Wot, const float* bo, float* out)
{
    __shared__ __attribute__((aligned(16))) char smem[65536];
    gemm_body<0, 0, 1, 0>(smem, ybb, ybb, Wot, Wot, bo, out, nullptr,
                          blockIdx.y * 128, blockIdx.x * 128, 1024, 1024);
}

// ================= flash attention v5 (r10's 87 µs kernel, verbatim) =========
// Transposed dataflow (S^T = K Q^T, O^T = V^T P^T), cross-quad shfl row
// reductions, 16B-aligned P rows (stride 72), DOUBLE-BUFFERED K/V staging:
// issue next step's global loads right after the barrier, compute current step,
// ds_write the prefetch after compute. Barrier at top of step j guarantees all
// waves finished reading buf[j^1] in step j-1 -> safe to overwrite.
// (v6's 3-blocks/CU single-buffer variant was SLOWER: 99 vs 87 — the extra
// barrier/step cost more than the occupancy bought. (256,4) spilled: r11.)
#define KSP 72
#define PSP 72
__global__ __launch_bounds__(256, 2)
void attn_v5(const __bf16* __restrict__ qhi, const __bf16* __restrict__ qlo,
             const __bf16* __restrict__ khi, const __bf16* __restrict__ klo,
             const __bf16* __restrict__ vtg, __bf16* __restrict__ yb)
{
    __shared__ __attribute__((aligned(16))) __bf16 Kh2[2][64 * KSP];
    __shared__ __attribute__((aligned(16))) __bf16 Kl2[2][64 * KSP];
    __shared__ __attribute__((aligned(16))) __bf16 Vt2[2][64 * KSP];   // [d][key]
    __shared__ __attribute__((aligned(16))) __bf16 Pw[4][2][16 * PSP]; // [wave][frag][qrow][key]

    const int tid  = threadIdx.x;
    const int w    = tid >> 6;
    const int lane = tid & 63;
    const int l16  = lane & 15;
    const int quad = lane >> 4;

    // bh = g&31 (XCD-stable); tiles paired (15-2a, 2(a-8)) so co-resident pairs sum to 34 steps
    const int g  = blockIdx.x;
    const int bh = g & 31, a = g >> 5;
    const int tile = (a < 8) ? (15 - 2 * a) : (2 * (a - 8));
    const int b = bh >> 4, h = bh & 15;
    const int q0 = tile * 128;

    // Q B-frags (pre-scaled by QSCALE), 2 frags x 2 k-halves
    bf16x8 qh[2][2], ql[2][2];
#pragma unroll
    for (int f = 0; f < 2; ++f) {
        const int    qrow = q0 + 64 * f + 16 * w + l16;
        const size_t qoff = (size_t)(b * T_SEQ + qrow) * DM + h * HD;
#pragma unroll
        for (int s = 0; s < 2; ++s) {
            qh[f][s] = *(const bf16x8*)&qhi[qoff + s * 32 + quad * 8];
            ql[f][s] = *(const bf16x8*)&qlo[qoff + s * 32 + quad * 8];
        }
    }

    f32x4 o[2][4];
#pragma unroll
    for (int f = 0; f < 2; ++f)
#pragma unroll
        for (int i = 0; i < 4; ++i) o[f][i] = (f32x4)0.0f;
    float m_i[2] = {-1e30f, -1e30f}, l_i[2] = {0.f, 0.f};

    const int srow = tid >> 3, sc8 = (tid & 7) * 8;
    bf16x8 kr[2], lr[2], vr[2];

    // prologue: stage step 0 into buf 0
#pragma unroll
    for (int it = 0; it < 2; ++it) {
        int    r  = it * 32 + srow;
        size_t gk = (size_t)(b * T_SEQ + r) * DM + h * HD + sc8;
        kr[it] = *(const bf16x8*)&khi[gk];
        lr[it] = *(const bf16x8*)&klo[gk];
        vr[it] = *(const bf16x8*)&vtg[(size_t)(bh * HD + r) * T_SEQ + sc8];
    }
#pragma unroll
    for (int it = 0; it < 2; ++it) {
        int r = it * 32 + srow;
        *(bf16x8*)&Kh2[0][r * KSP + sc8] = kr[it];
        *(bf16x8*)&Kl2[0][r * KSP + sc8] = lr[it];
        *(bf16x8*)&Vt2[0][r * KSP + sc8] = vr[it];
    }

    const int jmax = q0 + 64;
    for (int j0 = 0; j0 <= jmax; j0 += 64) {
        const int  cur  = (j0 >> 6) & 1;
        const bool act0 = (j0 <= q0);   // frag0 fully masked on final step
        const bool pre  = (j0 + 64 <= jmax);
        __syncthreads();                // buf[cur] visible; buf[cur^1] free

        // issue next step's global loads (latency overlaps compute below)
        if (pre) {
#pragma unroll
            for (int it = 0; it < 2; ++it) {
                int    r  = it * 32 + srow;
                size_t gk = (size_t)(b * T_SEQ + j0 + 64 + r) * DM + h * HD + sc8;
                kr[it] = *(const bf16x8*)&khi[gk];
                lr[it] = *(const bf16x8*)&klo[gk];
                vr[it] = *(const bf16x8*)&vtg[(size_t)(bh * HD + r) * T_SEQ + j0 + 64 + sc8];
            }
        }

        const __bf16* Kh = Kh2[cur];
        const __bf16* Kl = Kl2[cur];
        const __bf16* Vt = Vt2[cur];

        // S^T = K Q^T: rows=keys (kc,quad,reg), cols=qrows (l16)
        f32x4 sa[2][4];
#pragma unroll
        for (int f = 0; f < 2; ++f)
#pragma unroll
            for (int i = 0; i < 4; ++i) sa[f][i] = (f32x4)0.0f;
#pragma unroll
        for (int s = 0; s < 2; ++s) {
#pragma unroll
            for (int kc = 0; kc < 4; ++kc) {
                bf16x8 kh = *(const bf16x8*)&Kh[(kc * 16 + l16) * KSP + s * 32 + quad * 8];
                bf16x8 kv = *(const bf16x8*)&Kl[(kc * 16 + l16) * KSP + s * 32 + quad * 8];
                sa[1][kc] = mfma16(kh, qh[1][s], sa[1][kc]);
                sa[1][kc] = mfma16(kv, qh[1][s], sa[1][kc]);
                sa[1][kc] = mfma16(kh, ql[1][s], sa[1][kc]);
                if (act0) {
                    sa[0][kc] = mfma16(kh, qh[0][s], sa[0][kc]);
                    sa[0][kc] = mfma16(kv, qh[0][s], sa[0][kc]);
                    sa[0][kc] = mfma16(kh, ql[0][s], sa[0][kc]);
                }
            }
        }

        // online softmax; row state shared across the 4 quads holding this
        // q-row's keys -> cross-quad shfl_xor(16,32) reductions
#pragma unroll
        for (int f = 0; f < 2; ++f) {
            if (f == 0 && !act0) continue;
            const int  qrow = q0 + 64 * f + 16 * w + l16;
            const bool need = (j0 + 63 > q0 + 64 * f + 16 * w);
            if (need) {
#pragma unroll
                for (int kc = 0; kc < 4; ++kc)
#pragma unroll
                    for (int r = 0; r < 4; ++r)
                        if (j0 + kc * 16 + quad * 4 + r > qrow) sa[f][kc][r] = -1e30f;
            }
            float mx = -1e30f;
#pragma unroll
            for (int kc = 0; kc < 4; ++kc)
#pragma unroll
                for (int r = 0; r < 4; ++r) mx = fmaxf(mx, sa[f][kc][r]);
            mx = fmaxf(mx, __shfl_xor(mx, 16));
            mx = fmaxf(mx, __shfl_xor(mx, 32));
            float mn    = fmaxf(fmaxf(m_i[f], mx), -1e20f);
            float alpha = exp2f(m_i[f] - mn);
            m_i[f] = mn;
            float rs = 0.f;
            __bf16* pw = &Pw[w][f][0];
#pragma unroll
            for (int kc = 0; kc < 4; ++kc) {
                float p0 = exp2f(sa[f][kc][0] - mn);
                float p1 = exp2f(sa[f][kc][1] - mn);
                float p2 = exp2f(sa[f][kc][2] - mn);
                float p3 = exp2f(sa[f][kc][3] - mn);
                rs += (p0 + p1) + (p2 + p3);
                bf16x4 pk = { (__bf16)p0, (__bf16)p1, (__bf16)p2, (__bf16)p3 };
                *(bf16x4*)&pw[l16 * PSP + kc * 16 + quad * 4] = pk;
            }
            rs += __shfl_xor(rs, 16);
            rs += __shfl_xor(rs, 32);
            l_i[f] = l_i[f] * alpha + rs;
#pragma unroll
            for (int dc = 0; dc < 4; ++dc) o[f][dc] *= alpha;
        }

        // O^T += V^T P^T: rows=d (dc,quad,reg), cols=qrows (l16)
#pragma unroll
        for (int s = 0; s < 2; ++s) {
            bf16x8 pb1 = *(const bf16x8*)&Pw[w][1][l16 * PSP + s * 32 + quad * 8];
            bf16x8 pb0;
            if (act0) pb0 = *(const bf16x8*)&Pw[w][0][l16 * PSP + s * 32 + quad * 8];
#pragma unroll
            for (int dc = 0; dc < 4; ++dc) {
                bf16x8 va = *(const bf16x8*)&Vt[(dc * 16 + l16) * KSP + s * 32 + quad * 8];
                o[1][dc] = mfma16(va, pb1, o[1][dc]);
                if (act0) o[0][dc] = mfma16(va, pb0, o[0][dc]);
            }
        }

        // commit the prefetch into the other buffer (after compute)
        if (pre) {
            __bf16* nKh = Kh2[cur ^ 1];
            __bf16* nKl = Kl2[cur ^ 1];
            __bf16* nVt = Vt2[cur ^ 1];
#pragma unroll
            for (int it = 0; it < 2; ++it) {
                int r = it * 32 + srow;
                *(bf16x8*)&nKh[r * KSP + sc8] = kr[it];
                *(bf16x8*)&nKl[r * KSP + sc8] = lr[it];
                *(bf16x8*)&nVt[r * KSP + sc8] = vr[it];
            }
        }
    }

    // epilogue: normalize, transpose via per-wave P buffer, coalesced store
#pragma unroll
    for (int f = 0; f < 2; ++f) {
        float   invl = 1.0f / l_i[f];
        __bf16* pw   = &Pw[w][f][0];
#pragma unroll
        for (int dc = 0; dc < 4; ++dc) {
            bf16x4 ov = { (__bf16)(o[f][dc][0] * invl), (__bf16)(o[f][dc][1] * invl),
                          (__bf16)(o[f][dc][2] * invl), (__bf16)(o[f][dc][3] * invl) };
            *(bf16x4*)&pw[l16 * PSP + dc * 16 + quad * 4] = ov;
        }
        const int qrl  = lane >> 2;          // 0..15
        const int dch  = (lane & 3) * 16;    // 0,16,32,48
        const int qrow = q0 + 64 * f + 16 * w + qrl;
        const __bf16* src = &pw[qrl * PSP + dch];
        __bf16*       dst = &yb[(size_t)(b * T_SEQ + qrow) * DM + h * HD + dch];
        *(bf16x8*)dst       = *(const bf16x8*)src;
        *(bf16x8*)(dst + 8) = *(const bf16x8*)(src + 8);
    }
}

extern "C" void kernel_launch(void* const* d_in, const int* in_sizes, int n_in,
                              void* d_out, int out_size, void* d_ws, size_t ws_size,
                              hipStream_t stream)
{
    (void)in_sizes; (void)n_in; (void)out_size; (void)ws_size;

    const float* x   = (const float*)d_in[0];
    const float* Wq  = (const float*)d_in[2];
    const float* bq  = (const float*)d_in[3];
    const float* Wkv = (const float*)d_in[4];
    const float* bkv = (const float*)d_in[5];
    const float* Wk  = (const float*)d_in[6];
    const float* bk  = (const float*)d_in[7];
    const float* Wv  = (const float*)d_in[8];
    const float* bv  = (const float*)d_in[9];
    const float* Wo  = (const float*)d_in[10];
    const float* bo  = (const float*)d_in[11];
    const float* Wkr = (const float*)d_in[12];

    const int    BT = 2 * T_SEQ;   // 4096
    const size_t MB = 1024 * 1024;
    char* base = (char*)d_ws;

    __bf16* xhi    = (__bf16*)(base +  0 * MB);
    __bf16* xlo    = (__bf16*)(base +  8 * MB);
    __bf16* qhi    = (__bf16*)(base + 16 * MB);
    __bf16* qlo    = (__bf16*)(base + 24 * MB);
    __bf16* Wqt_h  = (__bf16*)(base + 32 * MB);
    __bf16* Wqt_l  = (__bf16*)(base + 34 * MB);
    __bf16* Wkvt_h = (__bf16*)(base + 36 * MB);
    __bf16* Wkvt_l = (__bf16*)(base + 37 * MB);
    __bf16* kvhi   = (__bf16*)(base + 38 * MB);
    __bf16* kvlo   = (__bf16*)(base + 40 * MB);
    __bf16* W2t_h  = (__bf16*)(base + 42 * MB);
    __bf16* W2t_l  = (__bf16*)(base + 42 * MB + 512 * 1024);
    __bf16* Wvt    = (__bf16*)(base + 43 * MB);
    __bf16* Wot    = (__bf16*)(base + 43 * MB + 512 * 1024);
    float*  b2     = (float*) (base + 45 * MB + 512 * 1024);
    __bf16* vtg    = (__bf16*)(base +  8 * MB);               // overlays xlo (dead after gemm_qkv)
    __bf16* ybb    = (__bf16*)(base +  0 * MB);               // overlays xhi (dead after gemm_qkv)
    __bf16* khi    = (__bf16*)d_out;                          // d_out as scratch
    __bf16* klo    = (__bf16*)d_out + (size_t)BT * DM;        // overwritten by o gemm

    dim3 blk(256);
    prep<<<3716, blk, 0, stream>>>(x, Wq, Wkv, Wv, Wo, Wk, Wkr, bk,
                                   xhi, xlo, Wqt_h, Wqt_l, Wkvt_h, Wkvt_l,
                                   Wvt, Wot, W2t_h, W2t_l, b2);
    gemm_qkv<<<dim3(10, 32), blk, 0, stream>>>(xhi, xlo, Wqt_h, Wqt_l, bq, qhi, qlo,
                                               Wkvt_h, Wkvt_l, bkv, kvhi, kvlo);
    gemm_kv2<<<dim3(16, 32), blk, 0, stream>>>(kvhi, kvlo, W2t_h, W2t_l, b2,
                                               khi, klo, Wvt, bv, vtg);
    attn_v5<<<512, blk, 0, stream>>>(qhi, qlo, khi, klo, vtg, ybb);
    gemm_o<<<dim3(8, 32), blk, 0, stream>>>(ybb, Wot, bo, (float*)d_out);
}